// Round 5
// baseline (2481.485 us; speedup 1.0000x reference)
//
#include <hip/hip_runtime.h>
#include <hip/hip_bf16.h>
#include <cstdint>
#include <cstddef>

// Problem constants (match reference)
#define B_CL   8
#define NPTS   2048
#define S1CNT  1024
#define S2CNT  256
#define KNBR   64

// Exact f32 squared distance in the reference's summation order:
// ((dx*dx + dy*dy) + dz*dz), each op IEEE-rounded (no fma contraction).
__device__ __forceinline__ float dist2_exact(float ax, float ay, float az,
                                             float bx, float by, float bz) {
    float dx = __fsub_rn(ax, bx);
    float dy = __fsub_rn(ay, by);
    float dz = __fsub_rn(az, bz);
    return __fadd_rn(__fadd_rn(__fmul_rn(dx, dx), __fmul_rn(dy, dy)), __fmul_rn(dz, dz));
}

// 64-lane max-reduce of a u64 key via DPP (VALU-speed cross-lane, no LDS).
// Result valid in lane 63 of each wave. All lanes must be active.
__device__ __forceinline__ unsigned long long wave_max_u64(unsigned long long k) {
#define DPP_STEP(CTRL) {                                                            \
    unsigned lo = (unsigned)k, hi = (unsigned)(k >> 32);                            \
    unsigned nlo = (unsigned)__builtin_amdgcn_update_dpp((int)lo, (int)lo, CTRL,    \
                                                         0xf, 0xf, false);          \
    unsigned nhi = (unsigned)__builtin_amdgcn_update_dpp((int)hi, (int)hi, CTRL,    \
                                                         0xf, 0xf, false);          \
    unsigned long long nk = ((unsigned long long)nhi << 32) | nlo;                  \
    if (nk > k) k = nk;                                                             \
}
    DPP_STEP(0x111);  // row_shr:1
    DPP_STEP(0x112);  // row_shr:2
    DPP_STEP(0x114);  // row_shr:4
    DPP_STEP(0x118);  // row_shr:8
    DPP_STEP(0x142);  // row_bcast:15
    DPP_STEP(0x143);  // row_bcast:31
#undef DPP_STEP
    return k;
}

// ---------------------------------------------------------------------------
// Farthest point sampling. One block of 256 threads (4 waves) per cloud.
// Replicates: sel[0]=0; d = |p - p0|^2; loop: nxt = argmax(d) (first max);
// d = min(d, |p - p_nxt|^2). Only c_pos = pos[sel] is needed downstream.
//
// Latency-critical design: ONE barrier per iteration (parity double-buffered
// wave-winner slots), DPP-based wave argmax, no global stores inside the loop
// (selected coords buffered in LDS, dumped at the end) so __syncthreads never
// waits on an HBM write drain.
// ---------------------------------------------------------------------------
template <int N, int S>
__global__ __launch_bounds__(256) void fps_kernel(const float* __restrict__ pos,
                                                  float* __restrict__ cpos) {
    constexpr int PPT = N / 256;
    __shared__ float px[N], py[N], pz[N];
    __shared__ float sel[S * 3];
    __shared__ unsigned long long kbuf[2][4];

    const int b   = blockIdx.x;
    const int tid = threadIdx.x;
    const float* P = pos + (size_t)b * N * 3;

    float ox[PPT], oy[PPT], oz[PPT], d[PPT];
    for (int j = 0; j < PPT; ++j) {
        int idx = tid + 256 * j;
        float x = P[idx * 3 + 0];
        float y = P[idx * 3 + 1];
        float z = P[idx * 3 + 2];
        px[idx] = x; py[idx] = y; pz[idx] = z;
        ox[j] = x; oy[j] = y; oz[j] = z;
        d[j] = 1e30f;
    }
    __syncthreads();

    float cx = px[0], cy = py[0], cz = pz[0];
    if (tid == 0) { sel[0] = cx; sel[1] = cy; sel[2] = cz; }

    for (int i = 1; i < S; ++i) {
        // update distances with current point; local argmax (strict > keeps
        // the first/min index since idx increases with j)
        float bv = -1.0f;
        int   bi = 0;
        #pragma unroll
        for (int j = 0; j < PPT; ++j) {
            int idx = tid + 256 * j;
            float dd = dist2_exact(ox[j], oy[j], oz[j], cx, cy, cz);
            float nd = fminf(d[j], dd);
            d[j] = nd;
            if (nd > bv) { bv = nd; bi = idx; }
        }
        // pack (d2, ~idx): u64 max == (max d2, then min idx). d2 >= 0 so the
        // f32 bit pattern is order-preserving.
        unsigned long long key =
            ((unsigned long long)__float_as_uint(bv) << 32) | (unsigned)(~bi);
        key = wave_max_u64(key);

        const int par = i & 1;
        if ((tid & 63) == 63) kbuf[par][tid >> 6] = key;
        __syncthreads();

        // every thread resolves the block winner redundantly (no 2nd barrier;
        // parity double-buffer makes next iteration's overwrite safe)
        unsigned long long kk = kbuf[par][0];
        unsigned long long k1 = kbuf[par][1];
        unsigned long long k2 = kbuf[par][2];
        unsigned long long k3 = kbuf[par][3];
        if (k1 > kk) kk = k1;
        if (k2 > kk) kk = k2;
        if (k3 > kk) kk = k3;
        int nxt = (int)(~(unsigned)kk);

        cx = px[nxt]; cy = py[nxt]; cz = pz[nxt];
        if (tid == 0) {
            sel[i * 3 + 0] = cx;
            sel[i * 3 + 1] = cy;
            sel[i * 3 + 2] = cz;
        }
    }
    __syncthreads();
    float* cp = cpos + (size_t)b * S * 3;
    for (int j = tid; j < S * 3; j += 256) cp[j] = sel[j];
}

// ---------------------------------------------------------------------------
// Radius neighbor search: up to KNBR nearest points within sqrt(rr) of each
// centroid (exact top_k semantics: K smallest d2, ties -> smaller index).
// One block of 256 threads per centroid. N = number of candidate points.
// ---------------------------------------------------------------------------
template <int N>
__global__ __launch_bounds__(256) void radius_kernel(const float* __restrict__ pos,
                                                     const float* __restrict__ cpos,
                                                     int M, float rr,
                                                     int* __restrict__ nbr,
                                                     int* __restrict__ cnt) {
    __shared__ unsigned long long list[N];
    __shared__ int c_sh;

    const int bm  = blockIdx.x;      // b*M + m
    const int b   = bm / M;
    const int tid = threadIdx.x;
    const float* P = pos + (size_t)b * N * 3;

    const float cx = cpos[bm * 3 + 0];
    const float cy = cpos[bm * 3 + 1];
    const float cz = cpos[bm * 3 + 2];

    if (tid == 0) c_sh = 0;
    __syncthreads();

    for (int i = tid; i < N; i += 256) {
        float d2 = dist2_exact(cx, cy, cz, P[i * 3], P[i * 3 + 1], P[i * 3 + 2]);
        if (d2 <= rr) {
            int slot = atomicAdd(&c_sh, 1);
            list[slot] = ((unsigned long long)__float_as_uint(d2) << 32) | (unsigned int)i;
        }
    }
    __syncthreads();
    int C = c_sh;

    if (C <= KNBR) {
        if (tid < C) nbr[(size_t)bm * KNBR + tid] = (int)(list[tid] & 0xffffffffu);
        if (tid == 0) cnt[bm] = C;
        return;
    }

    // bitonic sort the C candidates (pad to pow2) ascending by (d2, idx)
    int P2 = 1;
    while (P2 < C) P2 <<= 1;
    for (int i = C + tid; i < P2; i += 256) list[i] = ~0ULL;
    __syncthreads();
    for (int k = 2; k <= P2; k <<= 1) {
        for (int j = k >> 1; j > 0; j >>= 1) {
            for (int i = tid; i < P2; i += 256) {
                int l = i ^ j;
                if (l > i) {
                    unsigned long long a = list[i], bb = list[l];
                    bool up = ((i & k) == 0);
                    if ((a > bb) == up) { list[i] = bb; list[l] = a; }
                }
            }
            __syncthreads();
        }
    }
    if (tid < KNBR) nbr[(size_t)bm * KNBR + tid] = (int)(list[tid] & 0xffffffffu);
    if (tid == 0) cnt[bm] = KNBR;
}

// ---------------------------------------------------------------------------
// SA1 PointNetConv: MLP [3 -> 64 -> 64 -> 128] per edge, max-aggregate.
// One block of 256 threads per centroid.
// ---------------------------------------------------------------------------
__global__ __launch_bounds__(256) void conv1_kernel(const float* __restrict__ pos,
                                                    const float* __restrict__ cpos,
                                                    const int* __restrict__ nbr,
                                                    const int* __restrict__ cnt,
                                                    const float* __restrict__ W1, const float* __restrict__ b1,
                                                    const float* __restrict__ W2, const float* __restrict__ b2,
                                                    const float* __restrict__ W3, const float* __restrict__ b3,
                                                    float* __restrict__ hout) {
    __shared__ float a0[KNBR][3];
    __shared__ float a1[KNBR][64];
    __shared__ float a2[KNBR][64];
    __shared__ float buf[2][128];
    __shared__ int   snbr[KNBR];

    const int bm  = blockIdx.x;      // b*S1 + m
    const int b   = bm / S1CNT;
    const int tid = threadIdx.x;
    const int C   = cnt[bm];

    const float cx = cpos[bm * 3 + 0];
    const float cy = cpos[bm * 3 + 1];
    const float cz = cpos[bm * 3 + 2];

    if (tid < C) snbr[tid] = nbr[(size_t)bm * KNBR + tid];
    __syncthreads();
    if (tid < C) {
        int n = snbr[tid];
        const float* pp = pos + ((size_t)b * NPTS + n) * 3;
        a0[tid][0] = pp[0] - cx;
        a0[tid][1] = pp[1] - cy;
        a0[tid][2] = pp[2] - cz;
    }
    __syncthreads();

    for (int e = tid; e < C * 64; e += 256) {
        int k = e >> 6, j = e & 63;
        float v = b1[j];
        #pragma unroll
        for (int i = 0; i < 3; ++i) v += a0[k][i] * W1[i * 64 + j];
        a1[k][j] = fmaxf(v, 0.f);
    }
    __syncthreads();

    for (int e = tid; e < C * 64; e += 256) {
        int k = e >> 6, j = e & 63;
        float v = b2[j];
        #pragma unroll 8
        for (int i = 0; i < 64; ++i) v += a1[k][i] * W2[i * 64 + j];
        a2[k][j] = fmaxf(v, 0.f);
    }
    __syncthreads();

    const int jj = tid & 127, half = tid >> 7;
    float vmax = -1e30f;
    for (int k = half; k < C; k += 2) {
        float v = b3[jj];
        #pragma unroll 8
        for (int i = 0; i < 64; ++i) v += a2[k][i] * W3[i * 128 + jj];
        vmax = fmaxf(vmax, v);
    }
    buf[half][jj] = vmax;
    __syncthreads();
    if (tid < 128) hout[(size_t)bm * 128 + tid] = fmaxf(buf[0][tid], buf[1][tid]);
}

// ---------------------------------------------------------------------------
// SA2 PointNetConv: MLP [131 -> 128 -> 128 -> 256] per edge, max-aggregate.
// One block of 256 threads per centroid; neighbors processed in chunks of 32.
// ---------------------------------------------------------------------------
__global__ __launch_bounds__(256) void conv2_kernel(const float* __restrict__ x,      // h1 [B,S1,128]
                                                    const float* __restrict__ ppos,   // cpos1 [B,S1,3]
                                                    const float* __restrict__ cpos,   // cpos2 [B,S2,3]
                                                    const int* __restrict__ nbr,
                                                    const int* __restrict__ cnt,
                                                    const float* __restrict__ W1, const float* __restrict__ b1,
                                                    const float* __restrict__ W2, const float* __restrict__ b2,
                                                    const float* __restrict__ W3, const float* __restrict__ b3,
                                                    float* __restrict__ hout) {
    __shared__ float a0[32][128];
    __shared__ float rel[32][3];
    __shared__ float a1[32][128];
    __shared__ float a2[32][128];
    __shared__ int   snbr[KNBR];

    const int bm  = blockIdx.x;      // b*S2 + m
    const int b   = bm / S2CNT;
    const int tid = threadIdx.x;
    const int C   = cnt[bm];

    const float cx = cpos[bm * 3 + 0];
    const float cy = cpos[bm * 3 + 1];
    const float cz = cpos[bm * 3 + 2];

    if (tid < C) snbr[tid] = nbr[(size_t)bm * KNBR + tid];
    float vmax = -1e30f;   // this thread's output channel = tid
    __syncthreads();

    for (int c0 = 0; c0 < C; c0 += 32) {
        const int nk = min(32, C - c0);
        for (int e = tid; e < nk * 128; e += 256) {
            int k = e >> 7, i = e & 127;
            int n = snbr[c0 + k];
            a0[k][i] = x[((size_t)b * S1CNT + n) * 128 + i];
        }
        if (tid < nk * 3) {
            int k = tid / 3, i = tid % 3;
            int n = snbr[c0 + k];
            float cc = (i == 0) ? cx : (i == 1) ? cy : cz;
            rel[k][i] = ppos[((size_t)b * S1CNT + n) * 3 + i] - cc;
        }
        __syncthreads();

        for (int e = tid; e < nk * 128; e += 256) {
            int k = e >> 7, j = e & 127;
            float v = b1[j];
            #pragma unroll 8
            for (int i = 0; i < 128; ++i) v += a0[k][i] * W1[i * 128 + j];
            v += rel[k][0] * W1[128 * 128 + j];
            v += rel[k][1] * W1[129 * 128 + j];
            v += rel[k][2] * W1[130 * 128 + j];
            a1[k][j] = fmaxf(v, 0.f);
        }
        __syncthreads();

        for (int e = tid; e < nk * 128; e += 256) {
            int k = e >> 7, j = e & 127;
            float v = b2[j];
            #pragma unroll 8
            for (int i = 0; i < 128; ++i) v += a1[k][i] * W2[i * 128 + j];
            a2[k][j] = fmaxf(v, 0.f);
        }
        __syncthreads();

        for (int k = 0; k < nk; ++k) {
            float v = b3[tid];
            #pragma unroll 8
            for (int i = 0; i < 128; ++i) v += a2[k][i] * W3[i * 256 + tid];
            vmax = fmaxf(vmax, v);
        }
        __syncthreads();
    }
    hout[(size_t)bm * 256 + tid] = vmax;
}

// ---------------------------------------------------------------------------
// Global MLP [259 -> 256 -> 512 -> 1024] per S2 row, atomic-max into encoded
// uint buffer (order-preserving float encoding; max is order-independent).
// ---------------------------------------------------------------------------
__device__ __forceinline__ unsigned enc_f32(float f) {
    unsigned u = __float_as_uint(f);
    return (u & 0x80000000u) ? ~u : (u | 0x80000000u);
}

__global__ __launch_bounds__(256) void gmax_init_kernel(unsigned* __restrict__ gmax) {
    gmax[blockIdx.x * 256 + threadIdx.x] = 0u;   // encodes below any finite float
}

__global__ __launch_bounds__(256) void mlp3_kernel(const float* __restrict__ h2,
                                                   const float* __restrict__ cpos2,
                                                   const float* __restrict__ W1, const float* __restrict__ b1,
                                                   const float* __restrict__ W2, const float* __restrict__ b2,
                                                   const float* __restrict__ W3, const float* __restrict__ b3,
                                                   unsigned* __restrict__ gmax) {
    __shared__ float in[259];
    __shared__ float a1[256];
    __shared__ float a2[512];

    const int bm  = blockIdx.x;     // b*S2 + s
    const int bcl = bm / S2CNT;
    const int tid = threadIdx.x;

    in[tid] = h2[(size_t)bm * 256 + tid];
    if (tid < 3) in[256 + tid] = cpos2[bm * 3 + tid];
    __syncthreads();

    {
        float v = b1[tid];
        #pragma unroll 8
        for (int i = 0; i < 259; ++i) v += in[i] * W1[i * 256 + tid];
        a1[tid] = fmaxf(v, 0.f);
    }
    __syncthreads();
    {
        float v0 = b2[tid], v1 = b2[tid + 256];
        #pragma unroll 8
        for (int i = 0; i < 256; ++i) {
            float h = a1[i];
            v0 += h * W2[i * 512 + tid];
            v1 += h * W2[i * 512 + tid + 256];
        }
        a2[tid] = fmaxf(v0, 0.f);
        a2[tid + 256] = fmaxf(v1, 0.f);
    }
    __syncthreads();
    for (int q = 0; q < 4; ++q) {
        int jj = tid + 256 * q;
        float v = b3[jj];
        #pragma unroll 8
        for (int i = 0; i < 512; ++i) v += a2[i] * W3[i * 1024 + jj];
        atomicMax(&gmax[(size_t)bcl * 1024 + jj], enc_f32(v));
    }
}

__global__ __launch_bounds__(256) void gmax_decode_kernel(const unsigned* __restrict__ gmax,
                                                          float* __restrict__ out) {
    int t = blockIdx.x * 256 + threadIdx.x;
    unsigned u = gmax[t];
    out[t] = (u & 0x80000000u) ? __uint_as_float(u ^ 0x80000000u) : __uint_as_float(~u);
}

// ---------------------------------------------------------------------------
extern "C" void kernel_launch(void* const* d_in, const int* in_sizes, int n_in,
                              void* d_out, int out_size, void* d_ws, size_t ws_size,
                              hipStream_t stream) {
    (void)in_sizes; (void)n_in; (void)out_size; (void)ws_size;

    const float* pos = (const float*)d_in[0];
    const float* W1a = (const float*)d_in[1];  const float* b1a = (const float*)d_in[2];
    const float* W1b = (const float*)d_in[3];  const float* b1b = (const float*)d_in[4];
    const float* W1c = (const float*)d_in[5];  const float* b1c = (const float*)d_in[6];
    const float* W2a = (const float*)d_in[7];  const float* b2a = (const float*)d_in[8];
    const float* W2b = (const float*)d_in[9];  const float* b2b = (const float*)d_in[10];
    const float* W2c = (const float*)d_in[11]; const float* b2c = (const float*)d_in[12];
    const float* W3a = (const float*)d_in[13]; const float* b3a = (const float*)d_in[14];
    const float* W3b = (const float*)d_in[15]; const float* b3b = (const float*)d_in[16];
    const float* W3c = (const float*)d_in[17]; const float* b3c = (const float*)d_in[18];

    float* out = (float*)d_out;

    char* ws = (char*)d_ws;
    auto alloc = [&](size_t bytes) {
        char* p = ws;
        ws += (bytes + 255) & ~(size_t)255;
        return p;
    };
    float*    cpos1 = (float*)   alloc((size_t)B_CL * S1CNT * 3 * 4);
    int*      nbr1  = (int*)     alloc((size_t)B_CL * S1CNT * KNBR * 4);
    int*      cnt1  = (int*)     alloc((size_t)B_CL * S1CNT * 4);
    float*    h1    = (float*)   alloc((size_t)B_CL * S1CNT * 128 * 4);
    float*    cpos2 = (float*)   alloc((size_t)B_CL * S2CNT * 3 * 4);
    int*      nbr2  = (int*)     alloc((size_t)B_CL * S2CNT * KNBR * 4);
    int*      cnt2  = (int*)     alloc((size_t)B_CL * S2CNT * 4);
    float*    h2    = (float*)   alloc((size_t)B_CL * S2CNT * 256 * 4);
    unsigned* gmax  = (unsigned*)alloc((size_t)B_CL * 1024 * 4);

    const float RR1 = (float)(0.2 * 0.2);   // matches f32(np/jax r*r)
    const float RR2 = (float)(0.4 * 0.4);

    // SA module 1
    fps_kernel<NPTS, S1CNT><<<B_CL, 256, 0, stream>>>(pos, cpos1);
    radius_kernel<NPTS><<<B_CL * S1CNT, 256, 0, stream>>>(pos, cpos1, S1CNT, RR1, nbr1, cnt1);
    conv1_kernel<<<B_CL * S1CNT, 256, 0, stream>>>(pos, cpos1, nbr1, cnt1,
                                                   W1a, b1a, W1b, b1b, W1c, b1c, h1);
    // SA module 2
    fps_kernel<S1CNT, S2CNT><<<B_CL, 256, 0, stream>>>(cpos1, cpos2);
    radius_kernel<S1CNT><<<B_CL * S2CNT, 256, 0, stream>>>(cpos1, cpos2, S2CNT, RR2, nbr2, cnt2);
    conv2_kernel<<<B_CL * S2CNT, 256, 0, stream>>>(h1, cpos1, cpos2, nbr2, cnt2,
                                                   W2a, b2a, W2b, b2b, W2c, b2c, h2);
    // Global MLP + max pool
    gmax_init_kernel<<<(B_CL * 1024) / 256, 256, 0, stream>>>(gmax);
    mlp3_kernel<<<B_CL * S2CNT, 256, 0, stream>>>(h2, cpos2,
                                                  W3a, b3a, W3b, b3b, W3c, b3c, gmax);
    gmax_decode_kernel<<<(B_CL * 1024) / 256, 256, 0, stream>>>(gmax, out);
}

// Round 6
// 1834.240 us; speedup vs baseline: 1.3529x; 1.3529x over previous
//
#include <hip/hip_runtime.h>
#include <hip/hip_bf16.h>
#include <cstdint>
#include <cstddef>

// Problem constants (match reference)
#define B_CL   8
#define NPTS   2048
#define S1CNT  1024
#define S2CNT  256
#define KNBR   64

// Exact f32 squared distance in the reference's summation order:
// ((dx*dx + dy*dy) + dz*dz), each op IEEE-rounded (no fma contraction).
__device__ __forceinline__ float dist2_exact(float ax, float ay, float az,
                                             float bx, float by, float bz) {
    float dx = __fsub_rn(ax, bx);
    float dy = __fsub_rn(ay, by);
    float dz = __fsub_rn(az, bz);
    return __fadd_rn(__fadd_rn(__fmul_rn(dx, dx), __fmul_rn(dy, dy)), __fmul_rn(dz, dz));
}

// 64-lane max-reduce of a u64 key via DPP (VALU-speed cross-lane, no LDS).
// Result valid in lane 63 of each wave. All lanes must be active.
__device__ __forceinline__ unsigned long long wave_max_u64(unsigned long long k) {
#define DPP_STEP(CTRL) {                                                            \
    unsigned lo = (unsigned)k, hi = (unsigned)(k >> 32);                            \
    unsigned nlo = (unsigned)__builtin_amdgcn_update_dpp((int)lo, (int)lo, CTRL,    \
                                                         0xf, 0xf, false);          \
    unsigned nhi = (unsigned)__builtin_amdgcn_update_dpp((int)hi, (int)hi, CTRL,    \
                                                         0xf, 0xf, false);          \
    unsigned long long nk = ((unsigned long long)nhi << 32) | nlo;                  \
    if (nk > k) k = nk;                                                             \
}
    DPP_STEP(0x111);  // row_shr:1
    DPP_STEP(0x112);  // row_shr:2
    DPP_STEP(0x114);  // row_shr:4
    DPP_STEP(0x118);  // row_shr:8
    DPP_STEP(0x142);  // row_bcast:15
    DPP_STEP(0x143);  // row_bcast:31
#undef DPP_STEP
    return k;
}

// ---------------------------------------------------------------------------
// Farthest point sampling. One block of 256 threads (4 waves) per cloud.
// (unchanged from round 1 — latency-optimized, bit-exact selection)
// ---------------------------------------------------------------------------
template <int N, int S>
__global__ __launch_bounds__(256) void fps_kernel(const float* __restrict__ pos,
                                                  float* __restrict__ cpos) {
    constexpr int PPT = N / 256;
    __shared__ float px[N], py[N], pz[N];
    __shared__ float sel[S * 3];
    __shared__ unsigned long long kbuf[2][4];

    const int b   = blockIdx.x;
    const int tid = threadIdx.x;
    const float* P = pos + (size_t)b * N * 3;

    float ox[PPT], oy[PPT], oz[PPT], d[PPT];
    for (int j = 0; j < PPT; ++j) {
        int idx = tid + 256 * j;
        float x = P[idx * 3 + 0];
        float y = P[idx * 3 + 1];
        float z = P[idx * 3 + 2];
        px[idx] = x; py[idx] = y; pz[idx] = z;
        ox[j] = x; oy[j] = y; oz[j] = z;
        d[j] = 1e30f;
    }
    __syncthreads();

    float cx = px[0], cy = py[0], cz = pz[0];
    if (tid == 0) { sel[0] = cx; sel[1] = cy; sel[2] = cz; }

    for (int i = 1; i < S; ++i) {
        float bv = -1.0f;
        int   bi = 0;
        #pragma unroll
        for (int j = 0; j < PPT; ++j) {
            int idx = tid + 256 * j;
            float dd = dist2_exact(ox[j], oy[j], oz[j], cx, cy, cz);
            float nd = fminf(d[j], dd);
            d[j] = nd;
            if (nd > bv) { bv = nd; bi = idx; }
        }
        unsigned long long key =
            ((unsigned long long)__float_as_uint(bv) << 32) | (unsigned)(~bi);
        key = wave_max_u64(key);

        const int par = i & 1;
        if ((tid & 63) == 63) kbuf[par][tid >> 6] = key;
        __syncthreads();

        unsigned long long kk = kbuf[par][0];
        unsigned long long k1 = kbuf[par][1];
        unsigned long long k2 = kbuf[par][2];
        unsigned long long k3 = kbuf[par][3];
        if (k1 > kk) kk = k1;
        if (k2 > kk) kk = k2;
        if (k3 > kk) kk = k3;
        int nxt = (int)(~(unsigned)kk);

        cx = px[nxt]; cy = py[nxt]; cz = pz[nxt];
        if (tid == 0) {
            sel[i * 3 + 0] = cx;
            sel[i * 3 + 1] = cy;
            sel[i * 3 + 2] = cz;
        }
    }
    __syncthreads();
    float* cp = cpos + (size_t)b * S * 3;
    for (int j = tid; j < S * 3; j += 256) cp[j] = sel[j];
}

// ---------------------------------------------------------------------------
// Radius neighbor search (unchanged — bit-exact top_k semantics).
// ---------------------------------------------------------------------------
template <int N>
__global__ __launch_bounds__(256) void radius_kernel(const float* __restrict__ pos,
                                                     const float* __restrict__ cpos,
                                                     int M, float rr,
                                                     int* __restrict__ nbr,
                                                     int* __restrict__ cnt) {
    __shared__ unsigned long long list[N];
    __shared__ int c_sh;

    const int bm  = blockIdx.x;      // b*M + m
    const int b   = bm / M;
    const int tid = threadIdx.x;
    const float* P = pos + (size_t)b * N * 3;

    const float cx = cpos[bm * 3 + 0];
    const float cy = cpos[bm * 3 + 1];
    const float cz = cpos[bm * 3 + 2];

    if (tid == 0) c_sh = 0;
    __syncthreads();

    for (int i = tid; i < N; i += 256) {
        float d2 = dist2_exact(cx, cy, cz, P[i * 3], P[i * 3 + 1], P[i * 3 + 2]);
        if (d2 <= rr) {
            int slot = atomicAdd(&c_sh, 1);
            list[slot] = ((unsigned long long)__float_as_uint(d2) << 32) | (unsigned int)i;
        }
    }
    __syncthreads();
    int C = c_sh;

    if (C <= KNBR) {
        if (tid < C) nbr[(size_t)bm * KNBR + tid] = (int)(list[tid] & 0xffffffffu);
        if (tid == 0) cnt[bm] = C;
        return;
    }

    int P2 = 1;
    while (P2 < C) P2 <<= 1;
    for (int i = C + tid; i < P2; i += 256) list[i] = ~0ULL;
    __syncthreads();
    for (int k = 2; k <= P2; k <<= 1) {
        for (int j = k >> 1; j > 0; j >>= 1) {
            for (int i = tid; i < P2; i += 256) {
                int l = i ^ j;
                if (l > i) {
                    unsigned long long a = list[i], bb = list[l];
                    bool up = ((i & k) == 0);
                    if ((a > bb) == up) { list[i] = bb; list[l] = a; }
                }
            }
            __syncthreads();
        }
    }
    if (tid < KNBR) nbr[(size_t)bm * KNBR + tid] = (int)(list[tid] & 0xffffffffu);
    if (tid == 0) cnt[bm] = KNBR;
}

// ---------------------------------------------------------------------------
// MLP layer engines: W column in registers (loaded once per block), activations
// transposed in LDS as act[i][k] (64 k-columns per row, 16B-group XOR swizzle:
// physical group = (k>>2) ^ (row & 15)). Compute reads are ds_read_b128 at a
// wave-uniform address -> LDS broadcast, conflict-free; 1 read feeds 4 FMAs.
// ---------------------------------------------------------------------------
#define ASWZ(row, k) ((row) * 64 + (((((k) >> 2) ^ ((row) & 15))) << 2) + ((k) & 3))

template <int K>
__device__ __forceinline__ void layer_fwd(const float* __restrict__ W, int ldw,
                                          const float* __restrict__ bias,
                                          const float* __restrict__ src,   // LDS [K][64] swz
                                          float* __restrict__ dst,         // LDS [N][64] swz
                                          int j, int kbase, int ngroups) {
    float w[K];
    #pragma unroll
    for (int i = 0; i < K; ++i) w[i] = W[i * ldw + j];
    const float bj = bias[j];
    for (int g = 0; g < ngroups; ++g) {
        const int kb = kbase + g * 4;
        const int gg = kb >> 2;
        float a0 = bj, a1 = bj, a2 = bj, a3 = bj;
        #pragma unroll
        for (int i = 0; i < K; ++i) {
            const float4 av = *(const float4*)&src[i * 64 + ((gg ^ (i & 15)) << 2)];
            a0 += av.x * w[i];
            a1 += av.y * w[i];
            a2 += av.z * w[i];
            a3 += av.w * w[i];
        }
        float4 o;
        o.x = fmaxf(a0, 0.f); o.y = fmaxf(a1, 0.f);
        o.z = fmaxf(a2, 0.f); o.w = fmaxf(a3, 0.f);
        *(float4*)&dst[j * 64 + ((gg ^ (j & 15)) << 2)] = o;
    }
}

template <int K>
__device__ __forceinline__ float layer_last(const float* __restrict__ W, int ldw,
                                            const float* __restrict__ bias,
                                            const float* __restrict__ src,
                                            int j, int kbase, int ngroups, int C) {
    float w[K];
    #pragma unroll
    for (int i = 0; i < K; ++i) w[i] = W[i * ldw + j];
    const float bj = bias[j];
    float vmax = -3.4e38f;
    for (int g = 0; g < ngroups; ++g) {
        const int kb = kbase + g * 4;
        const int gg = kb >> 2;
        float a0 = bj, a1 = bj, a2 = bj, a3 = bj;
        #pragma unroll
        for (int i = 0; i < K; ++i) {
            const float4 av = *(const float4*)&src[i * 64 + ((gg ^ (i & 15)) << 2)];
            a0 += av.x * w[i];
            a1 += av.y * w[i];
            a2 += av.z * w[i];
            a3 += av.w * w[i];
        }
        if (kb + 0 < C) vmax = fmaxf(vmax, a0);
        if (kb + 1 < C) vmax = fmaxf(vmax, a1);
        if (kb + 2 < C) vmax = fmaxf(vmax, a2);
        if (kb + 3 < C) vmax = fmaxf(vmax, a3);
    }
    return vmax;
}

// ---------------------------------------------------------------------------
// SA1 PointNetConv: MLP [3 -> 64 -> 64 -> 128], max-aggregate. 1 block/centroid.
// ---------------------------------------------------------------------------
__global__ __launch_bounds__(256) void conv1_kernel(const float* __restrict__ pos,
                                                    const float* __restrict__ cpos,
                                                    const int* __restrict__ nbr,
                                                    const int* __restrict__ cnt,
                                                    const float* __restrict__ W1, const float* __restrict__ b1,
                                                    const float* __restrict__ W2, const float* __restrict__ b2,
                                                    const float* __restrict__ W3, const float* __restrict__ b3,
                                                    float* __restrict__ hout) {
    __shared__ float act0[3 * 64];
    __shared__ float actA[64 * 64];
    __shared__ float actB[64 * 64];
    __shared__ float buf[2][128];
    __shared__ int   snbr[KNBR];

    const int bm  = blockIdx.x;          // b*S1 + m
    const int b   = bm >> 10;            // S1CNT = 1024
    const int tid = threadIdx.x;
    const int C   = cnt[bm];

    const float cx = cpos[bm * 3 + 0];
    const float cy = cpos[bm * 3 + 1];
    const float cz = cpos[bm * 3 + 2];

    if (tid < KNBR) snbr[tid] = (tid < C) ? nbr[(size_t)bm * KNBR + tid] : 0;
    __syncthreads();

    if (tid < KNBR) {
        const int k = tid;
        float r0 = 0.f, r1 = 0.f, r2 = 0.f;
        if (k < C) {
            const float* pp = pos + ((size_t)b * NPTS + snbr[k]) * 3;
            r0 = pp[0] - cx; r1 = pp[1] - cy; r2 = pp[2] - cz;
        }
        act0[ASWZ(0, k)] = r0;
        act0[ASWZ(1, k)] = r1;
        act0[ASWZ(2, k)] = r2;
    }
    __syncthreads();

    const int j  = tid & 63, kq = tid >> 6;     // 64 j x 4 k-quarters
    layer_fwd<3>(W1, 64, b1, act0, actA, j, kq * 16, 4);
    __syncthreads();
    layer_fwd<64>(W2, 64, b2, actA, actB, j, kq * 16, 4);
    __syncthreads();

    const int j2 = tid & 127, kh = tid >> 7;    // 128 j x 2 k-halves
    float vmax = layer_last<64>(W3, 128, b3, actB, j2, kh * 32, 8, C);
    buf[kh][j2] = vmax;
    __syncthreads();
    if (tid < 128) hout[(size_t)bm * 128 + tid] = fmaxf(buf[0][tid], buf[1][tid]);
}

// ---------------------------------------------------------------------------
// SA2 PointNetConv: MLP [131 -> 128 -> 128 -> 256], max-aggregate. 1 block/centroid.
// ---------------------------------------------------------------------------
__global__ __launch_bounds__(256) void conv2_kernel(const float* __restrict__ x,      // h1 [B,S1,128]
                                                    const float* __restrict__ ppos,   // cpos1 [B,S1,3]
                                                    const float* __restrict__ cpos,   // cpos2 [B,S2,3]
                                                    const int* __restrict__ nbr,
                                                    const int* __restrict__ cnt,
                                                    const float* __restrict__ W1, const float* __restrict__ b1,
                                                    const float* __restrict__ W2, const float* __restrict__ b2,
                                                    const float* __restrict__ W3, const float* __restrict__ b3,
                                                    float* __restrict__ hout) {
    __shared__ float actA[131 * 64];   // act0 (131 rows); reused as act2 (128 rows)
    __shared__ float actB[128 * 64];   // act1
    __shared__ int   snbr[KNBR];

    const int bm  = blockIdx.x;          // b*S2 + m
    const int b   = bm >> 8;             // S2CNT = 256
    const int tid = threadIdx.x;
    const int C   = cnt[bm];

    const float cx = cpos[bm * 3 + 0];
    const float cy = cpos[bm * 3 + 1];
    const float cz = cpos[bm * 3 + 2];

    if (tid < KNBR) snbr[tid] = (tid < C) ? nbr[(size_t)bm * KNBR + tid] : 0;
    __syncthreads();

    // stage x features transposed: rows 0..127 = x[nbr[k]][i], zero for k >= C
    for (int e = tid; e < 64 * 128; e += 256) {
        const int k = e >> 7, i = e & 127;
        float v = 0.f;
        if (k < C) v = x[((size_t)b * S1CNT + snbr[k]) * 128 + i];
        actA[ASWZ(i, k)] = v;
    }
    // rel rows 128..130
    if (tid < KNBR) {
        const int k = tid;
        float r0 = 0.f, r1 = 0.f, r2 = 0.f;
        if (k < C) {
            const float* pp = ppos + ((size_t)b * S1CNT + snbr[k]) * 3;
            r0 = pp[0] - cx; r1 = pp[1] - cy; r2 = pp[2] - cz;
        }
        actA[ASWZ(128, k)] = r0;
        actA[ASWZ(129, k)] = r1;
        actA[ASWZ(130, k)] = r2;
    }
    __syncthreads();

    const int j  = tid & 127, kh = tid >> 7;    // 128 j x 2 k-halves
    layer_fwd<131>(W1, 128, b1, actA, actB, j, kh * 32, 8);
    __syncthreads();
    layer_fwd<128>(W2, 128, b2, actB, actA, j, kh * 32, 8);   // act2 -> actA (act0 dead)
    __syncthreads();

    // layer 3: N=256, every thread owns one j, sweeps all 64 k
    float vmax = layer_last<128>(W3, 256, b3, actA, tid, 0, 16, C);
    hout[(size_t)bm * 256 + tid] = vmax;
}

// ---------------------------------------------------------------------------
// Global MLP [259 -> 256 -> 512 -> 1024]: 4 rows per block (4x W reuse),
// atomic-max into order-preserving-encoded uint buffer.
// ---------------------------------------------------------------------------
__device__ __forceinline__ unsigned enc_f32(float f) {
    unsigned u = __float_as_uint(f);
    return (u & 0x80000000u) ? ~u : (u | 0x80000000u);
}

__global__ __launch_bounds__(256) void gmax_init_kernel(unsigned* __restrict__ gmax) {
    gmax[blockIdx.x * 256 + threadIdx.x] = 0u;   // encodes below any finite float
}

__global__ __launch_bounds__(256) void mlp3_kernel(const float* __restrict__ h2,
                                                   const float* __restrict__ cpos2,
                                                   const float* __restrict__ W1, const float* __restrict__ b1,
                                                   const float* __restrict__ W2, const float* __restrict__ b2,
                                                   const float* __restrict__ W3, const float* __restrict__ b3,
                                                   unsigned* __restrict__ gmax) {
    __shared__ float in4[4][260];
    __shared__ float a1s[4][256];
    __shared__ float a2s[4][512];

    const int bm0 = blockIdx.x * 4;      // first of 4 consecutive s-rows (same cloud)
    const int bcl = bm0 >> 8;            // S2CNT = 256
    const int tid = threadIdx.x;

    #pragma unroll
    for (int r = 0; r < 4; ++r) {
        in4[r][tid] = h2[(size_t)(bm0 + r) * 256 + tid];
        if (tid < 3) in4[r][256 + tid] = cpos2[(bm0 + r) * 3 + tid];
    }
    __syncthreads();

    {   // L1: K=259, N=256; thread owns channel tid
        const float bj = b1[tid];
        float acc[4] = {bj, bj, bj, bj};
        for (int i = 0; i < 259; ++i) {
            const float w = W1[i * 256 + tid];
            #pragma unroll
            for (int r = 0; r < 4; ++r) acc[r] += in4[r][i] * w;
        }
        #pragma unroll
        for (int r = 0; r < 4; ++r) a1s[r][tid] = fmaxf(acc[r], 0.f);
    }
    __syncthreads();

    {   // L2: K=256, N=512; thread owns channels tid, tid+256
        const float bj0 = b2[tid], bj1 = b2[tid + 256];
        float acc0[4] = {bj0, bj0, bj0, bj0};
        float acc1[4] = {bj1, bj1, bj1, bj1};
        for (int i = 0; i < 256; ++i) {
            const float w0 = W2[i * 512 + tid];
            const float w1 = W2[i * 512 + tid + 256];
            #pragma unroll
            for (int r = 0; r < 4; ++r) {
                const float a = a1s[r][i];
                acc0[r] += a * w0;
                acc1[r] += a * w1;
            }
        }
        #pragma unroll
        for (int r = 0; r < 4; ++r) {
            a2s[r][tid]       = fmaxf(acc0[r], 0.f);
            a2s[r][tid + 256] = fmaxf(acc1[r], 0.f);
        }
    }
    __syncthreads();

    {   // L3: K=512, N=1024; thread owns channels tid + 256q, q=0..3
        float acc[4][4];
        #pragma unroll
        for (int q = 0; q < 4; ++q) {
            const float bj = b3[tid + 256 * q];
            #pragma unroll
            for (int r = 0; r < 4; ++r) acc[q][r] = bj;
        }
        for (int i = 0; i < 512; ++i) {
            float av[4];
            #pragma unroll
            for (int r = 0; r < 4; ++r) av[r] = a2s[r][i];
            #pragma unroll
            for (int q = 0; q < 4; ++q) {
                const float w = W3[i * 1024 + 256 * q + tid];
                #pragma unroll
                for (int r = 0; r < 4; ++r) acc[q][r] += av[r] * w;
            }
        }
        #pragma unroll
        for (int q = 0; q < 4; ++q)
            #pragma unroll
            for (int r = 0; r < 4; ++r)
                atomicMax(&gmax[(size_t)bcl * 1024 + 256 * q + tid], enc_f32(acc[q][r]));
    }
}

__global__ __launch_bounds__(256) void gmax_decode_kernel(const unsigned* __restrict__ gmax,
                                                          float* __restrict__ out) {
    int t = blockIdx.x * 256 + threadIdx.x;
    unsigned u = gmax[t];
    out[t] = (u & 0x80000000u) ? __uint_as_float(u ^ 0x80000000u) : __uint_as_float(~u);
}

// ---------------------------------------------------------------------------
extern "C" void kernel_launch(void* const* d_in, const int* in_sizes, int n_in,
                              void* d_out, int out_size, void* d_ws, size_t ws_size,
                              hipStream_t stream) {
    (void)in_sizes; (void)n_in; (void)out_size; (void)ws_size;

    const float* pos = (const float*)d_in[0];
    const float* W1a = (const float*)d_in[1];  const float* b1a = (const float*)d_in[2];
    const float* W1b = (const float*)d_in[3];  const float* b1b = (const float*)d_in[4];
    const float* W1c = (const float*)d_in[5];  const float* b1c = (const float*)d_in[6];
    const float* W2a = (const float*)d_in[7];  const float* b2a = (const float*)d_in[8];
    const float* W2b = (const float*)d_in[9];  const float* b2b = (const float*)d_in[10];
    const float* W2c = (const float*)d_in[11]; const float* b2c = (const float*)d_in[12];
    const float* W3a = (const float*)d_in[13]; const float* b3a = (const float*)d_in[14];
    const float* W3b = (const float*)d_in[15]; const float* b3b = (const float*)d_in[16];
    const float* W3c = (const float*)d_in[17]; const float* b3c = (const float*)d_in[18];

    float* out = (float*)d_out;

    char* ws = (char*)d_ws;
    auto alloc = [&](size_t bytes) {
        char* p = ws;
        ws += (bytes + 255) & ~(size_t)255;
        return p;
    };
    float*    cpos1 = (float*)   alloc((size_t)B_CL * S1CNT * 3 * 4);
    int*      nbr1  = (int*)     alloc((size_t)B_CL * S1CNT * KNBR * 4);
    int*      cnt1  = (int*)     alloc((size_t)B_CL * S1CNT * 4);
    float*    h1    = (float*)   alloc((size_t)B_CL * S1CNT * 128 * 4);
    float*    cpos2 = (float*)   alloc((size_t)B_CL * S2CNT * 3 * 4);
    int*      nbr2  = (int*)     alloc((size_t)B_CL * S2CNT * KNBR * 4);
    int*      cnt2  = (int*)     alloc((size_t)B_CL * S2CNT * 4);
    float*    h2    = (float*)   alloc((size_t)B_CL * S2CNT * 256 * 4);
    unsigned* gmax  = (unsigned*)alloc((size_t)B_CL * 1024 * 4);

    const float RR1 = (float)(0.2 * 0.2);   // matches f32(np/jax r*r)
    const float RR2 = (float)(0.4 * 0.4);

    // SA module 1
    fps_kernel<NPTS, S1CNT><<<B_CL, 256, 0, stream>>>(pos, cpos1);
    radius_kernel<NPTS><<<B_CL * S1CNT, 256, 0, stream>>>(pos, cpos1, S1CNT, RR1, nbr1, cnt1);
    conv1_kernel<<<B_CL * S1CNT, 256, 0, stream>>>(pos, cpos1, nbr1, cnt1,
                                                   W1a, b1a, W1b, b1b, W1c, b1c, h1);
    // SA module 2
    fps_kernel<S1CNT, S2CNT><<<B_CL, 256, 0, stream>>>(cpos1, cpos2);
    radius_kernel<S1CNT><<<B_CL * S2CNT, 256, 0, stream>>>(cpos1, cpos2, S2CNT, RR2, nbr2, cnt2);
    conv2_kernel<<<B_CL * S2CNT, 256, 0, stream>>>(h1, cpos1, cpos2, nbr2, cnt2,
                                                   W2a, b2a, W2b, b2b, W2c, b2c, h2);
    // Global MLP + max pool
    gmax_init_kernel<<<(B_CL * 1024) / 256, 256, 0, stream>>>(gmax);
    mlp3_kernel<<<(B_CL * S2CNT) / 4, 256, 0, stream>>>(h2, cpos2,
                                                        W3a, b3a, W3b, b3b, W3c, b3c, gmax);
    gmax_decode_kernel<<<(B_CL * 1024) / 256, 256, 0, stream>>>(gmax, out);
}

// Round 7
// 775.638 us; speedup vs baseline: 3.1993x; 2.3648x over previous
//
#include <hip/hip_runtime.h>
#include <hip/hip_bf16.h>
#include <cstdint>
#include <cstddef>

// Problem constants (match reference)
#define B_CL   8
#define NPTS   2048
#define S1CNT  1024
#define S2CNT  256
#define KNBR   64

typedef unsigned short ushort;
typedef __attribute__((ext_vector_type(8))) short short8b;  // 8 bf16 = MFMA A/B frag
typedef __attribute__((ext_vector_type(4))) float f32x4;    // MFMA C/D frag

__device__ __forceinline__ ushort f2bf(float f) {
    union { __hip_bfloat16 h; ushort u; } v;
    v.h = __float2bfloat16(f);
    return v.u;
}
__device__ __forceinline__ float bf2f(ushort u) {
    return __uint_as_float(((unsigned)u) << 16);
}
__device__ __forceinline__ short8b ldfrag(const ushort* p) {
    return *(const short8b*)p;
}
__device__ __forceinline__ f32x4 mfma16(short8b a, short8b b, f32x4 c) {
    return __builtin_amdgcn_mfma_f32_16x16x32_bf16(a, b, c, 0, 0, 0);
}

// Exact f32 squared distance in the reference's summation order.
__device__ __forceinline__ float dist2_exact(float ax, float ay, float az,
                                             float bx, float by, float bz) {
    float dx = __fsub_rn(ax, bx);
    float dy = __fsub_rn(ay, by);
    float dz = __fsub_rn(az, bz);
    return __fadd_rn(__fadd_rn(__fmul_rn(dx, dx), __fmul_rn(dy, dy)), __fmul_rn(dz, dz));
}

// 64-lane max-reduce of a u64 key via DPP. Result valid in lane 63.
__device__ __forceinline__ unsigned long long wave_max_u64(unsigned long long k) {
#define DPP_STEP(CTRL) {                                                            \
    unsigned lo = (unsigned)k, hi = (unsigned)(k >> 32);                            \
    unsigned nlo = (unsigned)__builtin_amdgcn_update_dpp((int)lo, (int)lo, CTRL,    \
                                                         0xf, 0xf, false);          \
    unsigned nhi = (unsigned)__builtin_amdgcn_update_dpp((int)hi, (int)hi, CTRL,    \
                                                         0xf, 0xf, false);          \
    unsigned long long nk = ((unsigned long long)nhi << 32) | nlo;                  \
    if (nk > k) k = nk;                                                             \
}
    DPP_STEP(0x111);  // row_shr:1
    DPP_STEP(0x112);  // row_shr:2
    DPP_STEP(0x114);  // row_shr:4
    DPP_STEP(0x118);  // row_shr:8
    DPP_STEP(0x142);  // row_bcast:15
    DPP_STEP(0x143);  // row_bcast:31
#undef DPP_STEP
    return k;
}

// ---------------------------------------------------------------------------
// Farthest point sampling (unchanged — latency-optimized, bit-exact selection)
// ---------------------------------------------------------------------------
template <int N, int S>
__global__ __launch_bounds__(256) void fps_kernel(const float* __restrict__ pos,
                                                  float* __restrict__ cpos) {
    constexpr int PPT = N / 256;
    __shared__ float px[N], py[N], pz[N];
    __shared__ float sel[S * 3];
    __shared__ unsigned long long kbuf[2][4];

    const int b   = blockIdx.x;
    const int tid = threadIdx.x;
    const float* P = pos + (size_t)b * N * 3;

    float ox[PPT], oy[PPT], oz[PPT], d[PPT];
    for (int j = 0; j < PPT; ++j) {
        int idx = tid + 256 * j;
        float x = P[idx * 3 + 0];
        float y = P[idx * 3 + 1];
        float z = P[idx * 3 + 2];
        px[idx] = x; py[idx] = y; pz[idx] = z;
        ox[j] = x; oy[j] = y; oz[j] = z;
        d[j] = 1e30f;
    }
    __syncthreads();

    float cx = px[0], cy = py[0], cz = pz[0];
    if (tid == 0) { sel[0] = cx; sel[1] = cy; sel[2] = cz; }

    for (int i = 1; i < S; ++i) {
        float bv = -1.0f;
        int   bi = 0;
        #pragma unroll
        for (int j = 0; j < PPT; ++j) {
            int idx = tid + 256 * j;
            float dd = dist2_exact(ox[j], oy[j], oz[j], cx, cy, cz);
            float nd = fminf(d[j], dd);
            d[j] = nd;
            if (nd > bv) { bv = nd; bi = idx; }
        }
        unsigned long long key =
            ((unsigned long long)__float_as_uint(bv) << 32) | (unsigned)(~bi);
        key = wave_max_u64(key);

        const int par = i & 1;
        if ((tid & 63) == 63) kbuf[par][tid >> 6] = key;
        __syncthreads();

        unsigned long long kk = kbuf[par][0];
        unsigned long long k1 = kbuf[par][1];
        unsigned long long k2 = kbuf[par][2];
        unsigned long long k3 = kbuf[par][3];
        if (k1 > kk) kk = k1;
        if (k2 > kk) kk = k2;
        if (k3 > kk) kk = k3;
        int nxt = (int)(~(unsigned)kk);

        cx = px[nxt]; cy = py[nxt]; cz = pz[nxt];
        if (tid == 0) {
            sel[i * 3 + 0] = cx;
            sel[i * 3 + 1] = cy;
            sel[i * 3 + 2] = cz;
        }
    }
    __syncthreads();
    float* cp = cpos + (size_t)b * S * 3;
    for (int j = tid; j < S * 3; j += 256) cp[j] = sel[j];
}

// ---------------------------------------------------------------------------
// Radius neighbor search (unchanged — bit-exact top_k semantics).
// ---------------------------------------------------------------------------
template <int N>
__global__ __launch_bounds__(256) void radius_kernel(const float* __restrict__ pos,
                                                     const float* __restrict__ cpos,
                                                     int M, float rr,
                                                     int* __restrict__ nbr,
                                                     int* __restrict__ cnt) {
    __shared__ unsigned long long list[N];
    __shared__ int c_sh;

    const int bm  = blockIdx.x;      // b*M + m
    const int b   = bm / M;
    const int tid = threadIdx.x;
    const float* P = pos + (size_t)b * N * 3;

    const float cx = cpos[bm * 3 + 0];
    const float cy = cpos[bm * 3 + 1];
    const float cz = cpos[bm * 3 + 2];

    if (tid == 0) c_sh = 0;
    __syncthreads();

    for (int i = tid; i < N; i += 256) {
        float d2 = dist2_exact(cx, cy, cz, P[i * 3], P[i * 3 + 1], P[i * 3 + 2]);
        if (d2 <= rr) {
            int slot = atomicAdd(&c_sh, 1);
            list[slot] = ((unsigned long long)__float_as_uint(d2) << 32) | (unsigned int)i;
        }
    }
    __syncthreads();
    int C = c_sh;

    if (C <= KNBR) {
        if (tid < C) nbr[(size_t)bm * KNBR + tid] = (int)(list[tid] & 0xffffffffu);
        if (tid == 0) cnt[bm] = C;
        return;
    }

    int P2 = 1;
    while (P2 < C) P2 <<= 1;
    for (int i = C + tid; i < P2; i += 256) list[i] = ~0ULL;
    __syncthreads();
    for (int k = 2; k <= P2; k <<= 1) {
        for (int j = k >> 1; j > 0; j >>= 1) {
            for (int i = tid; i < P2; i += 256) {
                int l = i ^ j;
                if (l > i) {
                    unsigned long long a = list[i], bb = list[l];
                    bool up = ((i & k) == 0);
                    if ((a > bb) == up) { list[i] = bb; list[l] = a; }
                }
            }
            __syncthreads();
        }
    }
    if (tid < KNBR) nbr[(size_t)bm * KNBR + tid] = (int)(list[tid] & 0xffffffffu);
    if (tid == 0) cnt[bm] = KNBR;
}

// ---------------------------------------------------------------------------
// Weight prep: W [K][N] f32  ->  Wt [N][Kpad] bf16 (zero-padded rows k >= K).
// Kpad = ceil32(K)+8 so MFMA a/b-frag LDS reads alias at most 2-way (free).
// grid = N blocks x 64 threads.
// ---------------------------------------------------------------------------
__global__ __launch_bounds__(64) void wprep_kernel(const float* __restrict__ W,
                                                   ushort* __restrict__ Wt,
                                                   int K, int N, int Kpad) {
    const int n = blockIdx.x;
    for (int k = threadIdx.x; k < Kpad; k += 64)
        Wt[(size_t)n * Kpad + k] = (k < K) ? f2bf(W[(size_t)k * N + n]) : (ushort)0;
}

// ---------------------------------------------------------------------------
// SA1 PointNetConv via MFMA: [3 -> 64 -> 64 -> 128] per centroid, max-agg.
// Block = 256 thr = 4 waves; waves split n-tiles (W loaded once per block);
// each wave computes all 4 m-tiles of its columns -> in-wave masked max.
// Kpads: L1 40, L2/L3 72.
// ---------------------------------------------------------------------------
__global__ __launch_bounds__(256) void conv1_kernel(const float* __restrict__ pos,
                                                    const float* __restrict__ cpos,
                                                    const int* __restrict__ nbr,
                                                    const int* __restrict__ cnt,
                                                    const ushort* __restrict__ Wt1, const float* __restrict__ b1,
                                                    const ushort* __restrict__ Wt2, const float* __restrict__ b2,
                                                    const ushort* __restrict__ Wt3, const float* __restrict__ b3,
                                                    ushort* __restrict__ h1) {
    __shared__ ushort act1[64 * 72];
    __shared__ ushort act2[64 * 72];
    __shared__ int    snbr[KNBR];

    const int bm  = blockIdx.x;          // b*S1 + m
    const int b   = bm >> 10;            // S1CNT = 1024
    const int tid = threadIdx.x;
    const int C   = cnt[bm];

    const float cx = cpos[bm * 3 + 0];
    const float cy = cpos[bm * 3 + 1];
    const float cz = cpos[bm * 3 + 2];

    if (tid < KNBR) snbr[tid] = (tid < C) ? nbr[(size_t)bm * KNBR + tid] : 0;
    __syncthreads();

    const int lane = tid & 63, w = tid >> 6;
    const int lrow = lane & 15;          // frag row/col within 16
    const int lk8  = (lane >> 4) * 8;    // frag k-base
    const int rbase = (lane >> 4) * 4;   // C-frag row base
    const f32x4 zz = {0.f, 0.f, 0.f, 0.f};

    // ---- build A0 frags in registers (K=3, k>=3 zero; lanes with k-base>=8 zero)
    short8b a0[4];
    #pragma unroll
    for (int mt = 0; mt < 4; ++mt) {
        short8b a = {0, 0, 0, 0, 0, 0, 0, 0};
        if (lane < 16) {
            const int nb = snbr[mt * 16 + lrow];
            const float* pp = pos + ((size_t)b * NPTS + nb) * 3;
            a[0] = (short)f2bf(pp[0] - cx);
            a[1] = (short)f2bf(pp[1] - cy);
            a[2] = (short)f2bf(pp[2] - cz);
        }
        a0[mt] = a;
    }

    // ---- L1: K=3 (1 kstep), N=64 -> 1 ntile per wave
    {
        const int nt = w;
        short8b bf = ldfrag(Wt1 + (size_t)(nt * 16 + lrow) * 40 + lk8);
        const float bj = b1[nt * 16 + lrow];
        #pragma unroll
        for (int mt = 0; mt < 4; ++mt) {
            f32x4 acc = mfma16(a0[mt], bf, zz);
            #pragma unroll
            for (int r = 0; r < 4; ++r) {
                const int row = mt * 16 + rbase + r;
                act1[row * 72 + nt * 16 + lrow] = f2bf(fmaxf(acc[r] + bj, 0.f));
            }
        }
    }
    __syncthreads();

    // ---- L2: K=64 (2 ksteps), N=64 -> 1 ntile per wave
    {
        short8b af[4][2];
        #pragma unroll
        for (int mt = 0; mt < 4; ++mt)
            #pragma unroll
            for (int ks = 0; ks < 2; ++ks)
                af[mt][ks] = ldfrag(&act1[(mt * 16 + lrow) * 72 + ks * 32 + lk8]);
        const int nt = w;
        short8b bf0 = ldfrag(Wt2 + (size_t)(nt * 16 + lrow) * 72 + 0  + lk8);
        short8b bf1 = ldfrag(Wt2 + (size_t)(nt * 16 + lrow) * 72 + 32 + lk8);
        const float bj = b2[nt * 16 + lrow];
        #pragma unroll
        for (int mt = 0; mt < 4; ++mt) {
            f32x4 acc = mfma16(af[mt][0], bf0, zz);
            acc = mfma16(af[mt][1], bf1, acc);
            #pragma unroll
            for (int r = 0; r < 4; ++r) {
                const int row = mt * 16 + rbase + r;
                act2[row * 72 + nt * 16 + lrow] = f2bf(fmaxf(acc[r] + bj, 0.f));
            }
        }
    }
    __syncthreads();

    // ---- L3: K=64 (2 ksteps), N=128 -> 2 ntiles per wave; no relu; masked max
    {
        short8b af[4][2];
        #pragma unroll
        for (int mt = 0; mt < 4; ++mt)
            #pragma unroll
            for (int ks = 0; ks < 2; ++ks)
                af[mt][ks] = ldfrag(&act2[(mt * 16 + lrow) * 72 + ks * 32 + lk8]);
        #pragma unroll
        for (int nti = 0; nti < 2; ++nti) {
            const int nt = w * 2 + nti;
            short8b bf0 = ldfrag(Wt3 + (size_t)(nt * 16 + lrow) * 72 + 0  + lk8);
            short8b bf1 = ldfrag(Wt3 + (size_t)(nt * 16 + lrow) * 72 + 32 + lk8);
            const float bj = b3[nt * 16 + lrow];
            float vm = -3.4e38f;
            #pragma unroll
            for (int mt = 0; mt < 4; ++mt) {
                f32x4 acc = mfma16(af[mt][0], bf0, zz);
                acc = mfma16(af[mt][1], bf1, acc);
                #pragma unroll
                for (int r = 0; r < 4; ++r) {
                    const int m = mt * 16 + rbase + r;
                    if (m < C) vm = fmaxf(vm, acc[r] + bj);
                }
            }
            vm = fmaxf(vm, __shfl_xor(vm, 16));
            vm = fmaxf(vm, __shfl_xor(vm, 32));
            if (lane < 16) h1[(size_t)bm * 128 + nt * 16 + lrow] = f2bf(vm);
        }
    }
}

// ---------------------------------------------------------------------------
// SA2 PointNetConv via MFMA: [131 -> 128 -> 128 -> 256] per centroid, max-agg.
// Kpads: L1 168 (5 ksteps cover k<160; 131..159 zero), L2/L3 136.
// act2 aliases act0 (dead after L1; barrier separates).
// ---------------------------------------------------------------------------
__global__ __launch_bounds__(256) void conv2_kernel(const ushort* __restrict__ x,     // h1 bf16 [B,S1,128]
                                                    const float* __restrict__ ppos,   // cpos1
                                                    const float* __restrict__ cpos,   // cpos2
                                                    const int* __restrict__ nbr,
                                                    const int* __restrict__ cnt,
                                                    const ushort* __restrict__ Wt1, const float* __restrict__ b1,
                                                    const ushort* __restrict__ Wt2, const float* __restrict__ b2,
                                                    const ushort* __restrict__ Wt3, const float* __restrict__ b3,
                                                    ushort* __restrict__ h2) {
    __shared__ ushort act0[64 * 168];    // also reused as act2 [64][136]
    __shared__ ushort act1[64 * 136];
    __shared__ int    snbr[KNBR];
    ushort* act2 = act0;

    const int bm  = blockIdx.x;          // b*S2 + m
    const int b   = bm >> 8;             // S2CNT = 256
    const int tid = threadIdx.x;
    const int C   = cnt[bm];

    const float cx = cpos[bm * 3 + 0];
    const float cy = cpos[bm * 3 + 1];
    const float cz = cpos[bm * 3 + 2];

    if (tid < KNBR) snbr[tid] = (tid < C) ? nbr[(size_t)bm * KNBR + tid] : 0;
    __syncthreads();

    // ---- stage act0: rows k=0..63 (neighbors), cols 0..127 = x feats, 128..130 rel, ..159 zero
    for (int e = tid; e < 1024; e += 256) {          // 64 rows x 16 chunks of 8 bf16
        const int k = e >> 4, c = (e & 15) * 8;
        short8b v = {0, 0, 0, 0, 0, 0, 0, 0};
        if (k < C) v = ldfrag(x + ((size_t)b * S1CNT + snbr[k]) * 128 + c);
        *(short8b*)&act0[k * 168 + c] = v;
    }
    if (tid < KNBR) {
        const int k = tid;
        float r0 = 0.f, r1 = 0.f, r2 = 0.f;
        if (k < C) {
            const float* pp = ppos + ((size_t)b * S1CNT + snbr[k]) * 3;
            r0 = pp[0] - cx; r1 = pp[1] - cy; r2 = pp[2] - cz;
        }
        act0[k * 168 + 128] = f2bf(r0);
        act0[k * 168 + 129] = f2bf(r1);
        act0[k * 168 + 130] = f2bf(r2);
        for (int c = 131; c < 160; ++c) act0[k * 168 + c] = 0;
    }
    __syncthreads();

    const int lane = tid & 63, w = tid >> 6;
    const int lrow = lane & 15;
    const int lk8  = (lane >> 4) * 8;
    const int rbase = (lane >> 4) * 4;
    const f32x4 zz = {0.f, 0.f, 0.f, 0.f};

    // ---- L1: K=131 (5 ksteps), N=128 -> 2 ntiles per wave
    {
        short8b af[4][5];
        #pragma unroll
        for (int mt = 0; mt < 4; ++mt)
            #pragma unroll
            for (int ks = 0; ks < 5; ++ks)
                af[mt][ks] = ldfrag(&act0[(mt * 16 + lrow) * 168 + ks * 32 + lk8]);
        #pragma unroll
        for (int nti = 0; nti < 2; ++nti) {
            const int nt = w * 2 + nti;
            f32x4 acc[4] = {zz, zz, zz, zz};
            #pragma unroll
            for (int ks = 0; ks < 5; ++ks) {
                short8b bf = ldfrag(Wt1 + (size_t)(nt * 16 + lrow) * 168 + ks * 32 + lk8);
                #pragma unroll
                for (int mt = 0; mt < 4; ++mt) acc[mt] = mfma16(af[mt][ks], bf, acc[mt]);
            }
            const float bj = b1[nt * 16 + lrow];
            #pragma unroll
            for (int mt = 0; mt < 4; ++mt)
                #pragma unroll
                for (int r = 0; r < 4; ++r) {
                    const int row = mt * 16 + rbase + r;
                    act1[row * 136 + nt * 16 + lrow] = f2bf(fmaxf(acc[mt][r] + bj, 0.f));
                }
        }
    }
    __syncthreads();

    // ---- L2: K=128 (4 ksteps), N=128 -> 2 ntiles per wave (act1 -> act2)
    {
        short8b af[4][4];
        #pragma unroll
        for (int mt = 0; mt < 4; ++mt)
            #pragma unroll
            for (int ks = 0; ks < 4; ++ks)
                af[mt][ks] = ldfrag(&act1[(mt * 16 + lrow) * 136 + ks * 32 + lk8]);
        #pragma unroll
        for (int nti = 0; nti < 2; ++nti) {
            const int nt = w * 2 + nti;
            f32x4 acc[4] = {zz, zz, zz, zz};
            #pragma unroll
            for (int ks = 0; ks < 4; ++ks) {
                short8b bf = ldfrag(Wt2 + (size_t)(nt * 16 + lrow) * 136 + ks * 32 + lk8);
                #pragma unroll
                for (int mt = 0; mt < 4; ++mt) acc[mt] = mfma16(af[mt][ks], bf, acc[mt]);
            }
            const float bj = b2[nt * 16 + lrow];
            #pragma unroll
            for (int mt = 0; mt < 4; ++mt)
                #pragma unroll
                for (int r = 0; r < 4; ++r) {
                    const int row = mt * 16 + rbase + r;
                    act2[row * 136 + nt * 16 + lrow] = f2bf(fmaxf(acc[mt][r] + bj, 0.f));
                }
        }
    }
    __syncthreads();

    // ---- L3: K=128 (4 ksteps), N=256 -> 4 ntiles per wave; no relu; masked max
    {
        short8b af[4][4];
        #pragma unroll
        for (int mt = 0; mt < 4; ++mt)
            #pragma unroll
            for (int ks = 0; ks < 4; ++ks)
                af[mt][ks] = ldfrag(&act2[(mt * 16 + lrow) * 136 + ks * 32 + lk8]);
        #pragma unroll
        for (int nti = 0; nti < 4; ++nti) {
            const int nt = w * 4 + nti;
            f32x4 acc[4] = {zz, zz, zz, zz};
            #pragma unroll
            for (int ks = 0; ks < 4; ++ks) {
                short8b bf = ldfrag(Wt3 + (size_t)(nt * 16 + lrow) * 136 + ks * 32 + lk8);
                #pragma unroll
                for (int mt = 0; mt < 4; ++mt) acc[mt] = mfma16(af[mt][ks], bf, acc[mt]);
            }
            const float bj = b3[nt * 16 + lrow];
            float vm = -3.4e38f;
            #pragma unroll
            for (int mt = 0; mt < 4; ++mt)
                #pragma unroll
                for (int r = 0; r < 4; ++r) {
                    const int m = mt * 16 + rbase + r;
                    if (m < C) vm = fmaxf(vm, acc[mt][r] + bj);
                }
            vm = fmaxf(vm, __shfl_xor(vm, 16));
            vm = fmaxf(vm, __shfl_xor(vm, 32));
            if (lane < 16) h2[(size_t)bm * 256 + nt * 16 + lrow] = f2bf(vm);
        }
    }
}

// ---------------------------------------------------------------------------
// Global MLP [259 -> 256 -> 512 -> 1024]: 4 rows per block, VALU fp32,
// atomic-max into order-preserving-encoded uint buffer. h2 input is bf16.
// ---------------------------------------------------------------------------
__device__ __forceinline__ unsigned enc_f32(float f) {
    unsigned u = __float_as_uint(f);
    return (u & 0x80000000u) ? ~u : (u | 0x80000000u);
}

__global__ __launch_bounds__(256) void gmax_init_kernel(unsigned* __restrict__ gmax) {
    gmax[blockIdx.x * 256 + threadIdx.x] = 0u;   // encodes below any finite float
}

__global__ __launch_bounds__(256) void mlp3_kernel(const ushort* __restrict__ h2,
                                                   const float* __restrict__ cpos2,
                                                   const float* __restrict__ W1, const float* __restrict__ b1,
                                                   const float* __restrict__ W2, const float* __restrict__ b2,
                                                   const float* __restrict__ W3, const float* __restrict__ b3,
                                                   unsigned* __restrict__ gmax) {
    __shared__ float in4[4][260];
    __shared__ float a1s[4][256];
    __shared__ float a2s[4][512];

    const int bm0 = blockIdx.x * 4;      // first of 4 consecutive s-rows (same cloud)
    const int bcl = bm0 >> 8;            // S2CNT = 256
    const int tid = threadIdx.x;

    #pragma unroll
    for (int r = 0; r < 4; ++r) {
        in4[r][tid] = bf2f(h2[(size_t)(bm0 + r) * 256 + tid]);
        if (tid < 3) in4[r][256 + tid] = cpos2[(bm0 + r) * 3 + tid];
    }
    __syncthreads();

    {   // L1: K=259, N=256
        const float bj = b1[tid];
        float acc[4] = {bj, bj, bj, bj};
        for (int i = 0; i < 259; ++i) {
            const float w = W1[i * 256 + tid];
            #pragma unroll
            for (int r = 0; r < 4; ++r) acc[r] += in4[r][i] * w;
        }
        #pragma unroll
        for (int r = 0; r < 4; ++r) a1s[r][tid] = fmaxf(acc[r], 0.f);
    }
    __syncthreads();

    {   // L2: K=256, N=512
        const float bj0 = b2[tid], bj1 = b2[tid + 256];
        float acc0[4] = {bj0, bj0, bj0, bj0};
        float acc1[4] = {bj1, bj1, bj1, bj1};
        for (int i = 0; i < 256; ++i) {
            const float w0 = W2[i * 512 + tid];
            const float w1 = W2[i * 512 + tid + 256];
            #pragma unroll
            for (int r = 0; r < 4; ++r) {
                const float a = a1s[r][i];
                acc0[r] += a * w0;
                acc1[r] += a * w1;
            }
        }
        #pragma unroll
        for (int r = 0; r < 4; ++r) {
            a2s[r][tid]       = fmaxf(acc0[r], 0.f);
            a2s[r][tid + 256] = fmaxf(acc1[r], 0.f);
        }
    }
    __syncthreads();

    {   // L3: K=512, N=1024
        float acc[4][4];
        #pragma unroll
        for (int q = 0; q < 4; ++q) {
            const float bj = b3[tid + 256 * q];
            #pragma unroll
            for (int r = 0; r < 4; ++r) acc[q][r] = bj;
        }
        for (int i = 0; i < 512; ++i) {
            float av[4];
            #pragma unroll
            for (int r = 0; r < 4; ++r) av[r] = a2s[r][i];
            #pragma unroll
            for (int q = 0; q < 4; ++q) {
                const float w = W3[i * 1024 + 256 * q + tid];
                #pragma unroll
                for (int r = 0; r < 4; ++r) acc[q][r] += av[r] * w;
            }
        }
        #pragma unroll
        for (int q = 0; q < 4; ++q)
            #pragma unroll
            for (int r = 0; r < 4; ++r)
                atomicMax(&gmax[(size_t)bcl * 1024 + 256 * q + tid], enc_f32(acc[q][r]));
    }
}

__global__ __launch_bounds__(256) void gmax_decode_kernel(const unsigned* __restrict__ gmax,
                                                          float* __restrict__ out) {
    int t = blockIdx.x * 256 + threadIdx.x;
    unsigned u = gmax[t];
    out[t] = (u & 0x80000000u) ? __uint_as_float(u ^ 0x80000000u) : __uint_as_float(~u);
}

// ---------------------------------------------------------------------------
extern "C" void kernel_launch(void* const* d_in, const int* in_sizes, int n_in,
                              void* d_out, int out_size, void* d_ws, size_t ws_size,
                              hipStream_t stream) {
    (void)in_sizes; (void)n_in; (void)out_size; (void)ws_size;

    const float* pos = (const float*)d_in[0];
    const float* W1a = (const float*)d_in[1];  const float* b1a = (const float*)d_in[2];
    const float* W1b = (const float*)d_in[3];  const float* b1b = (const float*)d_in[4];
    const float* W1c = (const float*)d_in[5];  const float* b1c = (const float*)d_in[6];
    const float* W2a = (const float*)d_in[7];  const float* b2a = (const float*)d_in[8];
    const float* W2b = (const float*)d_in[9];  const float* b2b = (const float*)d_in[10];
    const float* W2c = (const float*)d_in[11]; const float* b2c = (const float*)d_in[12];
    const float* W3a = (const float*)d_in[13]; const float* b3a = (const float*)d_in[14];
    const float* W3b = (const float*)d_in[15]; const float* b3b = (const float*)d_in[16];
    const float* W3c = (const float*)d_in[17]; const float* b3c = (const float*)d_in[18];

    float* out = (float*)d_out;

    char* ws = (char*)d_ws;
    auto alloc = [&](size_t bytes) {
        char* p = ws;
        ws += (bytes + 255) & ~(size_t)255;
        return p;
    };
    float*    cpos1 = (float*)   alloc((size_t)B_CL * S1CNT * 3 * 4);
    int*      nbr1  = (int*)     alloc((size_t)B_CL * S1CNT * KNBR * 4);
    int*      cnt1  = (int*)     alloc((size_t)B_CL * S1CNT * 4);
    ushort*   h1    = (ushort*)  alloc((size_t)B_CL * S1CNT * 128 * 2);
    float*    cpos2 = (float*)   alloc((size_t)B_CL * S2CNT * 3 * 4);
    int*      nbr2  = (int*)     alloc((size_t)B_CL * S2CNT * KNBR * 4);
    int*      cnt2  = (int*)     alloc((size_t)B_CL * S2CNT * 4);
    ushort*   h2    = (ushort*)  alloc((size_t)B_CL * S2CNT * 256 * 2);
    unsigned* gmax  = (unsigned*)alloc((size_t)B_CL * 1024 * 4);
    ushort*   Wt1a  = (ushort*)  alloc((size_t)64  * 40  * 2);
    ushort*   Wt1b  = (ushort*)  alloc((size_t)64  * 72  * 2);
    ushort*   Wt1c  = (ushort*)  alloc((size_t)128 * 72  * 2);
    ushort*   Wt2a  = (ushort*)  alloc((size_t)128 * 168 * 2);
    ushort*   Wt2b  = (ushort*)  alloc((size_t)128 * 136 * 2);
    ushort*   Wt2c  = (ushort*)  alloc((size_t)256 * 136 * 2);

    const float RR1 = (float)(0.2 * 0.2);
    const float RR2 = (float)(0.4 * 0.4);

    // weight prep (bf16 transpose, zero-padded)
    wprep_kernel<<<64,  64, 0, stream>>>(W1a, Wt1a, 3,   64,  40);
    wprep_kernel<<<64,  64, 0, stream>>>(W1b, Wt1b, 64,  64,  72);
    wprep_kernel<<<128, 64, 0, stream>>>(W1c, Wt1c, 64,  128, 72);
    wprep_kernel<<<128, 64, 0, stream>>>(W2a, Wt2a, 131, 128, 168);
    wprep_kernel<<<128, 64, 0, stream>>>(W2b, Wt2b, 128, 128, 136);
    wprep_kernel<<<256, 64, 0, stream>>>(W2c, Wt2c, 128, 256, 136);

    // SA module 1
    fps_kernel<NPTS, S1CNT><<<B_CL, 256, 0, stream>>>(pos, cpos1);
    radius_kernel<NPTS><<<B_CL * S1CNT, 256, 0, stream>>>(pos, cpos1, S1CNT, RR1, nbr1, cnt1);
    conv1_kernel<<<B_CL * S1CNT, 256, 0, stream>>>(pos, cpos1, nbr1, cnt1,
                                                   Wt1a, b1a, Wt1b, b1b, Wt1c, b1c, h1);
    // SA module 2
    fps_kernel<S1CNT, S2CNT><<<B_CL, 256, 0, stream>>>(cpos1, cpos2);
    radius_kernel<S1CNT><<<B_CL * S2CNT, 256, 0, stream>>>(cpos1, cpos2, S2CNT, RR2, nbr2, cnt2);
    conv2_kernel<<<B_CL * S2CNT, 256, 0, stream>>>(h1, cpos1, cpos2, nbr2, cnt2,
                                                   Wt2a, b2a, Wt2b, b2b, Wt2c, b2c, h2);
    // Global MLP + max pool
    gmax_init_kernel<<<(B_CL * 1024) / 256, 256, 0, stream>>>(gmax);
    mlp3_kernel<<<(B_CL * S2CNT) / 4, 256, 0, stream>>>(h2, cpos2,
                                                        W3a, b3a, W3b, b3b, W3c, b3c, gmax);
    gmax_decode_kernel<<<(B_CL * 1024) / 256, 256, 0, stream>>>(gmax, out);
}